// Round 15
// baseline (161.049 us; speedup 1.0000x reference)
//
#include <hip/hip_runtime.h>

// 10-qubit batched statevector simulator -- packed-f16, 2 samples per wave,
// 2 pairs per wave (grid-stride). State = h2 Hr[16],Hi[16]; each 32-bit VGPR
// holds {sampleA, sampleB} f16. Amp bits: 0..5 = lane bits, 6..9 = register
// index k. Qubit q (MSB-first) = amp bit 9-q.
//
// Round-15 vs round-14 (92 us rocprof, VALU 83%, occupancy 46% < 62.5% cap):
//  (a) 2 pairs per wave: setup amortized 2x, block-cycling rounds halved
//      (4096 -> 2048 blocks). No LDS tables / no launch_bounds (rounds 7-10
//      lessons) -- loop-carried state is one integer, VGPR should hold ~48.
//  (b) epilogue packed in v2f (f32 pk): both samples' contractions and
//      signed reductions in one stream; halves epilogue VALU arithmetic.
// Layer-0 CRY ring remains folded into the init product state (round 14).

namespace {

constexpr int NQB = 10;

typedef _Float16 h2 __attribute__((ext_vector_type(2)));
typedef float v2f __attribute__((ext_vector_type(2)));

__device__ __forceinline__ float h2_as_f(h2 v) { return __builtin_bit_cast(float, v); }
__device__ __forceinline__ h2 f_as_h2(float v) { return __builtin_bit_cast(h2, v); }

__device__ __forceinline__ h2 pk2(float a, float b) {
#if __has_builtin(__builtin_amdgcn_cvt_pkrtz)
  return __builtin_bit_cast(h2, __builtin_amdgcn_cvt_pkrtz(a, b));
#else
  h2 r; r.x = (_Float16)a; r.y = (_Float16)b; return r;
#endif
}

__device__ __forceinline__ h2 hsplat(float f) {
  const _Float16 h = (_Float16)f;
  h2 r; r.x = h; r.y = h; return r;
}

__device__ __forceinline__ h2 hsel(bool c, h2 a, h2 b) {
  return f_as_h2(c ? h2_as_f(a) : h2_as_f(b));
}

template<int CTRL>
__device__ __forceinline__ float dppf(float x) {
  return __uint_as_float((unsigned)__builtin_amdgcn_update_dpp(
      0, (int)__float_as_uint(x), CTRL, 0xF, 0xF, true));
}

// Partner value x[lane ^ (1<<P)] on a 32-bit container.
// P0,P1,P3: 1 DPP (VALU). P2,P4: ds_swizzle (DS). P5: ds_bpermute (DS).
template<int P>
__device__ __forceinline__ float xorf(float x, int bpa) {
  if constexpr (P == 0) {
    return dppf<0xB1>(x);                       // quad_perm [1,0,3,2] = XOR1
  } else if constexpr (P == 1) {
    return dppf<0x4E>(x);                       // quad_perm [2,3,0,1] = XOR2
  } else if constexpr (P == 2) {
    return __uint_as_float((unsigned)__builtin_amdgcn_ds_swizzle(
        (int)__float_as_uint(x), 0x101F));      // bitmode xor=4
  } else if constexpr (P == 3) {
    return dppf<0x128>(x);                      // row_ror:8 == XOR8 within row16
  } else if constexpr (P == 4) {
    return __uint_as_float((unsigned)__builtin_amdgcn_ds_swizzle(
        (int)__float_as_uint(x), 0x401F));      // bitmode xor=16
  } else {
    return __uint_as_float((unsigned)__builtin_amdgcn_ds_bpermute(
        bpa, (int)__float_as_uint(x)));         // bpa = (lane^32)<<2
  }
}

template<int P>
__device__ __forceinline__ h2 xorh(h2 v, int bpa) {
  return f_as_h2(xorf<P>(h2_as_f(v), bpa));
}

template<int P>
__device__ __forceinline__ v2f xor2(v2f v, int bpa) {
  v2f r;
  r.x = xorf<P>(v.x, bpa);
  r.y = xorf<P>(v.y, bpa);
  return r;
}

__device__ __forceinline__ float fsin_rev(float rev) {
#if __has_builtin(__builtin_amdgcn_sinf)
  return __builtin_amdgcn_sinf(rev);
#else
  return __sinf(rev * 6.2831853071795864769f);
#endif
}
__device__ __forceinline__ float fcos_rev(float rev) {
#if __has_builtin(__builtin_amdgcn_cosf)
  return __builtin_amdgcn_cosf(rev);
#else
  return __cosf(rev * 6.2831853071795864769f);
#endif
}

__device__ __forceinline__ float clamp01(float x) {
#if __has_builtin(__builtin_amdgcn_fmed3f)
  return __builtin_amdgcn_fmed3f(x, 0.0f, 1.0f);
#else
  return fminf(fmaxf(x, 0.0f), 1.0f);
#endif
}

__device__ __forceinline__ void cmulf(float& r, float& i, float br, float bi) {
  const float tr = r * br - i * bi;
  i = r * bi + i * br;
  r = tr;
}

__device__ __forceinline__ void cmulh(h2& r, h2& i, h2 br, h2 bi) {
  const h2 tr = r*br - i*bi;
  i = r*bi + i*br;
  r = tr;
}

// u = Rot_q * (cos, sin): both rows of the per-qubit init 2-vector pair
__device__ __forceinline__ void qubit_uv(const float* m, float x,
                                         float& u0r, float& u0i,
                                         float& u1r, float& u1i) {
  const float r = 0.25f * clamp01(x);
  const float fs = fsin_rev(r), fc = fcos_rev(r);
  u0r = m[0]*fc + m[2]*fs;  u0i = m[1]*fc + m[3]*fs;
  u1r = m[4]*fc + m[6]*fs;  u1i = m[5]*fc + m[7]*fs;
}

// lane fold with layer-0 CRY chain folded: pt = 0..4, gate e = 8-pt
// (ctrl bit pt+1, tgt bit pt); w = b_ctrl ? RY(th_e)*u : u, component b_tgt.
__device__ __forceinline__ void lane_fold_cry(const float* __restrict__ xin, int lane,
                                              const float (*gm)[8], const float (*gc0)[2],
                                              float& Lr, float& Li) {
  Lr = 1.0f; Li = 0.0f;
#pragma unroll
  for (int pt = 0; pt < 5; ++pt) {
    const int q = 9 - pt, e = 8 - pt;
    float u0r, u0i, u1r, u1i;
    qubit_uv(&gm[q][0], xin[q], u0r, u0i, u1r, u1i);
    const bool bt = (lane >> pt) & 1;
    const bool bc = (lane >> (pt + 1)) & 1;
    const float c = gc0[e][0];
    const float s = bt ? gc0[e][1] : -gc0[e][1];
    const float ubr = bt ? u1r : u0r, ubi = bt ? u1i : u0i;   // u[bt]
    const float uor = bt ? u0r : u1r, uoi = bt ? u0i : u1i;   // u[1-bt]
    const float vr = c*ubr + s*uor, vi = c*ubi + s*uoi;       // (RY u)[bt]
    const float wr = bc ? vr : ubr, wi = bc ? vi : ubi;
    if (pt == 0) { Lr = wr; Li = wi; }
    else cmulf(Lr, Li, wr, wi);
  }
}

// level tables for reg bits: w[j], j = (b_ctrl<<1)|b_tgt; u rows + v = RY(th)*u
__device__ __forceinline__ void level_tab(const float* m, float c, float s,
                                          float xa, float xb,
                                          h2 (&wr)[4], h2 (&wi)[4]) {
  float a0r, a0i, a1r, a1i, b0r, b0i, b1r, b1i;
  qubit_uv(m, xa, a0r, a0i, a1r, a1i);
  qubit_uv(m, xb, b0r, b0i, b1r, b1i);
  const float va0r = c*a0r - s*a1r, va0i = c*a0i - s*a1i;
  const float va1r = s*a0r + c*a1r, va1i = s*a0i + c*a1i;
  const float vb0r = c*b0r - s*b1r, vb0i = c*b0i - s*b1i;
  const float vb1r = s*b0r + c*b1r, vb1i = s*b0i + c*b1i;
  wr[0] = pk2(a0r, b0r);  wi[0] = pk2(a0i, b0i);   // bc=0, bt=0
  wr[1] = pk2(a1r, b1r);  wi[1] = pk2(a1i, b1i);   // bc=0, bt=1
  wr[2] = pk2(va0r, vb0r); wi[2] = pk2(va0i, vb0i); // bc=1, bt=0
  wr[3] = pk2(va1r, vb1r); wi[3] = pk2(va1i, vb1i); // bc=1, bt=1
}

// ---- layer-1 gates ----

__device__ __forceinline__ void apply_diag16(h2 (&Hr)[16], h2 (&Hi)[16],
                                             h2 zr, h2 zi, const h2 (*zk)[2]) {
#pragma unroll
  for (int k = 0; k < 16; ++k) {
    const h2 kc = zk[k][0], ks = zk[k][1];
    const h2 cr = zr*kc - zi*ks;
    const h2 ci = zi*kc + zr*ks;
    const h2 tr = cr*Hr[k] - ci*Hi[k];
    const h2 ti = ci*Hr[k] + cr*Hi[k];
    Hr[k] = tr;  Hi[k] = ti;
  }
}

template<int J>
__device__ __forceinline__ void ry_reg16(h2 (&Hr)[16], h2 (&Hi)[16], h2 c, h2 s) {
#pragma unroll
  for (int k0 = 0; k0 < 16; ++k0) {
    if (k0 & J) continue;
    const int k1 = k0 | J;
    const h2 a0r = Hr[k0], a1r = Hr[k1], a0i = Hi[k0], a1i = Hi[k1];
    Hr[k0] = c*a0r - s*a1r;  Hr[k1] = s*a0r + c*a1r;
    Hi[k0] = c*a0i - s*a1i;  Hi[k1] = s*a0i + c*a1i;
  }
}

template<int P>
__device__ __forceinline__ void ry_lane16(h2 (&Hr)[16], h2 (&Hi)[16], h2 c, h2 ss,
                                          int bpa) {
#pragma unroll
  for (int k = 0; k < 16; ++k) {
    const h2 pr = xorh<P>(Hr[k], bpa);
    const h2 pi = xorh<P>(Hi[k], bpa);
    Hr[k] = c*Hr[k] + ss*pr;
    Hi[k] = c*Hi[k] + ss*pi;
  }
}

template<int CB, int J>
__device__ __forceinline__ void cry_rr(h2 (&Hr)[16], h2 (&Hi)[16], h2 c, h2 s) {
#pragma unroll
  for (int k0 = 0; k0 < 16; ++k0) {
    if ((k0 & J) || !(k0 & CB)) continue;
    const int k1 = k0 | J;
    const h2 a0r = Hr[k0], a1r = Hr[k1], a0i = Hi[k0], a1i = Hi[k1];
    Hr[k0] = c*a0r - s*a1r;  Hr[k1] = s*a0r + c*a1r;
    Hi[k0] = c*a0i - s*a1i;  Hi[k1] = s*a0i + c*a1i;
  }
}

__device__ __forceinline__ void cry_k0_l5(h2 (&Hr)[16], h2 (&Hi)[16], h2 c, h2 s,
                                          int lane, int bpa) {
  const h2 ss = hsel((lane >> 5) & 1, s, -s);
#pragma unroll
  for (int k = 1; k < 16; k += 2) {
    const h2 pr = xorh<5>(Hr[k], bpa);
    const h2 pi = xorh<5>(Hi[k], bpa);
    Hr[k] = c*Hr[k] + ss*pr;
    Hi[k] = c*Hi[k] + ss*pi;
  }
}

template<int PC, int PT>
__device__ __forceinline__ void cry_ll(h2 (&Hr)[16], h2 (&Hi)[16], h2 c, h2 s,
                                       h2 HONE, h2 HZERO, int lane, int bpa) {
  const bool ctrl = (lane >> PC) & 1;
  const h2 ce = hsel(ctrl, c, HONE);
  const h2 se = hsel(ctrl, s, HZERO);
  const h2 ss = hsel((lane >> PT) & 1, se, -se);
#pragma unroll
  for (int k = 0; k < 16; ++k) {
    const h2 pr = xorh<PT>(Hr[k], bpa);
    const h2 pi = xorh<PT>(Hi[k], bpa);
    Hr[k] = ce*Hr[k] + ss*pr;
    Hi[k] = ce*Hi[k] + ss*pi;
  }
}

__device__ __forceinline__ void cry_l0_r8(h2 (&Hr)[16], h2 (&Hi)[16], h2 c, h2 s,
                                          h2 HONE, h2 HZERO, int lane) {
  const bool ctrl = lane & 1;
  const h2 ce = hsel(ctrl, c, HONE);
  const h2 se = hsel(ctrl, s, HZERO);
#pragma unroll
  for (int k0 = 0; k0 < 8; ++k0) {
    const int k1 = k0 + 8;
    const h2 a0r = Hr[k0], a1r = Hr[k1], a0i = Hi[k0], a1i = Hi[k1];
    Hr[k0] = ce*a0r - se*a1r;  Hr[k1] = se*a0r + ce*a1r;
    Hi[k0] = ce*a0i - se*a1i;  Hi[k1] = se*a0i + ce*a1i;
  }
}

// ---- epilogue per PAIR: packed v2f {A,B} probs -> 10 expvals each, write ----
__device__ __forceinline__ void finish_pair(const v2f (&p)[16], int lane, int bpa,
                                            float* __restrict__ outA,
                                            float* __restrict__ outB) {
  v2f t[8], T[4];
  v2f e6 = {0.0f, 0.0f};
#pragma unroll
  for (int j = 0; j < 8; ++j) { t[j] = p[2*j] + p[2*j+1]; e6 += p[2*j] - p[2*j+1]; }
  v2f e7 = {0.0f, 0.0f};
#pragma unroll
  for (int j = 0; j < 4; ++j) { T[j] = t[2*j] + t[2*j+1]; e7 += t[2*j] - t[2*j+1]; }
  const v2f U0 = T[0] + T[1], U1 = T[2] + T[3];
  const v2f e8 = (T[0] - T[1]) + (T[2] - T[3]);
  const v2f tot = U0 + U1;
  const v2f e9 = U0 - U1;

  float sgn[6];
#pragma unroll
  for (int q = 0; q < 6; ++q) sgn[q] = ((lane >> q) & 1) ? -1.0f : 1.0f;

  v2f E[6];
  v2f tt = tot;
#define QSTEP(P)                                                   \
  {                                                                \
    const v2f pt = xor2<P>(tt, bpa);                               \
    E[P] = (tt - pt) * sgn[P];                                     \
    tt += pt;                                                      \
    _Pragma("unroll")                                              \
    for (int jj = 0; jj < P; ++jj) E[jj] += xor2<P>(E[jj], bpa);   \
  }
  QSTEP(0) QSTEP(1) QSTEP(2) QSTEP(3) QSTEP(4) QSTEP(5)
#undef QSTEP

  v2f a6 = e6, a7 = e7, a8 = e8, a9 = e9;
#define RSTEP(P)                 \
  a6 += xor2<P>(a6, bpa);        \
  a7 += xor2<P>(a7, bpa);        \
  a8 += xor2<P>(a8, bpa);        \
  a9 += xor2<P>(a9, bpa);
  RSTEP(0) RSTEP(1) RSTEP(2) RSTEP(3) RSTEP(4) RSTEP(5)
#undef RSTEP

  // out[q], q = 9 - p: q=0..3 <- bits 9,8,7,6 ; q=4..9 <- E[5..0]
  if (lane < 10) {
    v2f v = a9;
    v = (lane == 1) ? a8 : v;
    v = (lane == 2) ? a7 : v;
    v = (lane == 3) ? a6 : v;
    v = (lane == 4) ? E[5] : v;
    v = (lane == 5) ? E[4] : v;
    v = (lane == 6) ? E[3] : v;
    v = (lane == 7) ? E[2] : v;
    v = (lane == 8) ? E[1] : v;
    v = (lane == 9) ? E[0] : v;
    outA[lane] = v.x;
    outB[lane] = v.y;
  }
}

} // namespace

__global__ __launch_bounds__(256)
void qlayer_kernel(const float* __restrict__ inp,   // (B, 10)
                   const float* __restrict__ wt,    // (80,)
                   float* __restrict__ out,         // (B, 10)
                   int B)
{
  __shared__ float gm[10][8];        // layer-0 Rot matrices (f32)
  __shared__ float gc0[10][2];       // layer-0 CRY {c,s} f32 (used in init fold)
  __shared__ h2 gch1[10][2];         // layer-1 CRY {c,s} splats
  __shared__ h2 grot1h[10][2];       // layer-1 RY {c,s} splats
  __shared__ h2 gdk[2][16][2];       // layer-1 diag reg phases {c,s} splats
  __shared__ float gzlane[2][64][2]; // per-lane diag phase (c,s): [0]=phi,[1]=omega

  const int tid = threadIdx.x;

  // ---- setup (disjoint thread ranges) ----
  if (tid < 10) {
    // layer-0 Rot(phi, theta, omega) = RZ(omega) RY(theta) RZ(phi)
    const int w = 3 * tid;
    const float phi = wt[w], th = wt[w + 1], om = wt[w + 2];
    float s, c, sa, ca, sb, cb;
    __sincosf(0.5f * th, &s, &c);
    __sincosf(0.5f * (phi + om), &sa, &ca);
    __sincosf(0.5f * (phi - om), &sb, &cb);
    gm[tid][0] =  c * ca;  gm[tid][1] = -c * sa;   // u00
    gm[tid][2] = -s * cb;  gm[tid][3] = -s * sb;   // u01
    gm[tid][4] =  s * cb;  gm[tid][5] = -s * sb;   // u10
    gm[tid][6] =  c * ca;  gm[tid][7] =  c * sa;   // u11
  } else if (tid >= 16 && tid < 26) {
    const int e = tid - 16;                        // layer-0 CRY
    float s, c;
    __sincosf(0.5f * wt[30 + e], &s, &c);
    gc0[e][0] = c;
    gc0[e][1] = s;
  } else if (tid >= 32 && tid < 42) {
    const int e = tid - 32;                        // layer-1 CRY
    float s, c;
    __sincosf(0.5f * wt[70 + e], &s, &c);
    gch1[e][0] = hsplat(c);
    gch1[e][1] = hsplat(s);
  } else if (tid >= 48 && tid < 58) {
    const int q = tid - 48;
    float s, c;
    __sincosf(0.5f * wt[41 + 3 * q], &s, &c);      // layer-1 theta_q
    grot1h[q][0] = hsplat(c);
    grot1h[q][1] = hsplat(s);
  } else if (tid >= 64 && tid < 96) {
    // layer-1 diag reg tables: k bit0<->q3(+9), bit1<->q2(+6), bit2<->q1(+3), bit3<->q0(+0)
    const int t = tid - 64;
    const int d = t >> 4, k = t & 15;
    const int wb = d ? 42 : 40;
    float ang = 0.0f;
    if (k & 1) ang += wt[wb + 9];
    if (k & 2) ang += wt[wb + 6];
    if (k & 4) ang += wt[wb + 3];
    if (k & 8) ang += wt[wb + 0];
    float s, c;
    __sincosf(ang, &s, &c);
    gdk[d][k][0] = hsplat(c);
    gdk[d][k][1] = hsplat(s);
  } else if (tid >= 128) {
    // per-lane diag phase (lane bit p <-> qubit 9-p)
    const int d = (tid - 128) >> 6, ln = tid & 63;
    const int wb = d ? 42 : 40;
    float ang = 0.0f;
    if (ln & 1)  ang += wt[wb + 27];
    if (ln & 2)  ang += wt[wb + 24];
    if (ln & 4)  ang += wt[wb + 21];
    if (ln & 8)  ang += wt[wb + 18];
    if (ln & 16) ang += wt[wb + 15];
    if (ln & 32) ang += wt[wb + 12];
    float s, c;
    __sincosf(ang, &s, &c);
    gzlane[d][ln][0] = c;
    gzlane[d][ln][1] = s;
  }
  __syncthreads();

  const int lane = tid & 63;
  const int bpa = (lane ^ 32) << 2;
  const int half = B >> 1;                       // 16384 pairs
  const int gw = blockIdx.x * 4 + (tid >> 6);    // 0..8191
  const int pstride = gridDim.x * 4;             // 8192

  const h2 HONE  = hsplat(1.0f);
  const h2 HZERO = hsplat(0.0f);

#pragma unroll 1
  for (int j = 0; j < 2; ++j) {
    const int pair = gw + j * pstride;
    if (pair >= half) break;
    const int sA = pair, sB = pair + half;
    const float* xA = inp + sA * NQB;
    const float* xB = inp + sB * NQB;

    // ---- init: product state through (embedding RY + layer-0 Rot + layer-0
    // CRY gates (0,1)..(8,9)), built as pair-factor product. ----

    // lane part (bits 0..4, gates e=8..4)
    float LrA, LiA, LrB, LiB;
    lane_fold_cry(xA, lane, gm, gc0, LrA, LiA);
    lane_fold_cry(xB, lane, gm, gc0, LrB, LiB);

    // W5: bit 5 factor w_5(b6, b5) -- gate e=3 (ctrl bit6=reg k0), qubit 4
    h2 W5ur, W5ui, W5vr, W5vi;
    {
      float a0r,a0i,a1r,a1i, b0r,b0i,b1r,b1i;
      qubit_uv(&gm[4][0], xA[4], a0r,a0i,a1r,a1i);
      qubit_uv(&gm[4][0], xB[4], b0r,b0i,b1r,b1i);
      const bool bt = (lane >> 5) & 1;
      const float c = gc0[3][0];
      const float s = bt ? gc0[3][1] : -gc0[3][1];
      const float uArr = bt ? a1r : a0r, uAri = bt ? a1i : a0i;
      const float uAor = bt ? a0r : a1r, uAoi = bt ? a0i : a1i;
      const float uBrr = bt ? b1r : b0r, uBri = bt ? b1i : b0i;
      const float uBor = bt ? b0r : b1r, uBoi = bt ? b0i : b1i;
      W5ur = pk2(uArr, uBrr);  W5ui = pk2(uAri, uBri);
      W5vr = pk2(c*uArr + s*uAor, c*uBrr + s*uBor);
      W5vi = pk2(c*uAri + s*uAoi, c*uBri + s*uBoi);
    }

    // seed: bit 9 (qubit 0): H[k=8*b9] = L * u9[b9]
    h2 Hr[16], Hi[16];
    {
      float a0r,a0i,a1r,a1i, b0r,b0i,b1r,b1i;
      qubit_uv(&gm[0][0], xA[0], a0r,a0i,a1r,a1i);
      qubit_uv(&gm[0][0], xB[0], b0r,b0i,b1r,b1i);
      float t0rA = LrA, t0iA = LiA;  cmulf(t0rA, t0iA, a0r, a0i);
      float t1rA = LrA, t1iA = LiA;  cmulf(t1rA, t1iA, a1r, a1i);
      float t0rB = LrB, t0iB = LiB;  cmulf(t0rB, t0iB, b0r, b0i);
      float t1rB = LrB, t1iB = LiB;  cmulf(t1rB, t1iB, b1r, b1i);
      Hr[0] = pk2(t0rA, t0rB);  Hi[0] = pk2(t0iA, t0iB);
      Hr[8] = pk2(t1rA, t1rB);  Hi[8] = pk2(t1iA, t1iB);
    }

    // level bit 8 (qubit 1, gate e=0, ctrl = bit 9): parents {0,8}
    {
      h2 wr[4], wi[4];
      level_tab(&gm[1][0], gc0[0][0], gc0[0][1], xA[1], xB[1], wr, wi);
      Hr[4]  = Hr[0]; Hi[4]  = Hi[0]; cmulh(Hr[4],  Hi[4],  wr[1], wi[1]);  // b9=0,b8=1
      cmulh(Hr[0],  Hi[0],  wr[0], wi[0]);                                  // b9=0,b8=0
      Hr[12] = Hr[8]; Hi[12] = Hi[8]; cmulh(Hr[12], Hi[12], wr[3], wi[3]);  // b9=1,b8=1
      cmulh(Hr[8],  Hi[8],  wr[2], wi[2]);                                  // b9=1,b8=0
    }

    // level bit 7 (qubit 2, gate e=1, ctrl = bit 8): parents {0,4,8,12}
    {
      h2 wr[4], wi[4];
      level_tab(&gm[2][0], gc0[1][0], gc0[1][1], xA[2], xB[2], wr, wi);
#pragma unroll
      for (int k = 0; k < 16; k += 4) {
        const int jj = ((k >> 2) & 1) << 1;          // b8
        Hr[k+2] = Hr[k]; Hi[k+2] = Hi[k]; cmulh(Hr[k+2], Hi[k+2], wr[jj|1], wi[jj|1]);
        cmulh(Hr[k], Hi[k], wr[jj], wi[jj]);
      }
    }

    // level bit 6 (qubit 3, gate e=2, ctrl = bit 7) x W5(b6): parents {0,2,..,14}
    {
      h2 wr[4], wi[4];
      level_tab(&gm[3][0], gc0[2][0], gc0[2][1], xA[3], xB[3], wr, wi);
      cmulh(wr[0], wi[0], W5ur, W5ui);
      cmulh(wr[1], wi[1], W5vr, W5vi);
      cmulh(wr[2], wi[2], W5ur, W5ui);
      cmulh(wr[3], wi[3], W5vr, W5vi);
#pragma unroll
      for (int k = 0; k < 16; k += 2) {
        const int jj = ((k >> 1) & 1) << 1;          // b7
        Hr[k+1] = Hr[k]; Hi[k+1] = Hi[k]; cmulh(Hr[k+1], Hi[k+1], wr[jj|1], wi[jj|1]);
        cmulh(Hr[k], Hi[k], wr[jj], wi[jj]);
      }
    }

    // ---- layer 0: final ring gate (9,0): ctrl lane bit 0, tgt reg bit 3 ----
    cry_l0_r8(Hr, Hi, hsplat(gc0[9][0]), hsplat(gc0[9][1]), HONE, HZERO, lane);

    // ---- layer 1: D_phi -> real RY layer -> D_omega -> CRY ring ----
    {
      const float2 zp = *(const float2*)&gzlane[0][lane][0];
      apply_diag16(Hr, Hi, hsplat(zp.x), hsplat(zp.y), &gdk[0][0]);
      ry_reg16<8>(Hr, Hi, grot1h[0][0], grot1h[0][1]);          // q=0, k3
      ry_reg16<4>(Hr, Hi, grot1h[1][0], grot1h[1][1]);          // q=1, k2
      ry_reg16<2>(Hr, Hi, grot1h[2][0], grot1h[2][1]);          // q=2, k1
      ry_reg16<1>(Hr, Hi, grot1h[3][0], grot1h[3][1]);          // q=3, k0
      {
        const h2 s5 = grot1h[4][1];
        ry_lane16<5>(Hr, Hi, grot1h[4][0], hsel((lane >> 5) & 1, s5, -s5), bpa);
        const h2 s4 = grot1h[5][1];
        ry_lane16<4>(Hr, Hi, grot1h[5][0], hsel((lane >> 4) & 1, s4, -s4), bpa);
        const h2 s3 = grot1h[6][1];
        ry_lane16<3>(Hr, Hi, grot1h[6][0], hsel((lane >> 3) & 1, s3, -s3), bpa);
        const h2 s2 = grot1h[7][1];
        ry_lane16<2>(Hr, Hi, grot1h[7][0], hsel((lane >> 2) & 1, s2, -s2), bpa);
        const h2 s1 = grot1h[8][1];
        ry_lane16<1>(Hr, Hi, grot1h[8][0], hsel((lane >> 1) & 1, s1, -s1), bpa);
        const h2 s0 = grot1h[9][1];
        ry_lane16<0>(Hr, Hi, grot1h[9][0], hsel(lane & 1, s0, -s0), bpa);
      }
      const float2 zo = *(const float2*)&gzlane[1][lane][0];
      apply_diag16(Hr, Hi, hsplat(zo.x), hsplat(zo.y), &gdk[1][0]);

      const h2 (*cc)[2] = &gch1[0];
      cry_rr<8, 4>(Hr, Hi, cc[0][0], cc[0][1]);                 // (q0,q1)
      cry_rr<4, 2>(Hr, Hi, cc[1][0], cc[1][1]);                 // (q1,q2)
      cry_rr<2, 1>(Hr, Hi, cc[2][0], cc[2][1]);                 // (q2,q3)
      cry_k0_l5   (Hr, Hi, cc[3][0], cc[3][1], lane, bpa);      // (q3,q4)
      cry_ll<5, 4>(Hr, Hi, cc[4][0], cc[4][1], HONE, HZERO, lane, bpa);
      cry_ll<4, 3>(Hr, Hi, cc[5][0], cc[5][1], HONE, HZERO, lane, bpa);
      cry_ll<3, 2>(Hr, Hi, cc[6][0], cc[6][1], HONE, HZERO, lane, bpa);
      cry_ll<2, 1>(Hr, Hi, cc[7][0], cc[7][1], HONE, HZERO, lane, bpa);
      cry_ll<1, 0>(Hr, Hi, cc[8][0], cc[8][1], HONE, HZERO, lane, bpa);
      cry_l0_r8   (Hr, Hi, cc[9][0], cc[9][1], HONE, HZERO, lane);  // (q9,q0)
    }

    // ---- probabilities (packed f32 {A,B}) and epilogue ----
    v2f p2[16];
#pragma unroll
    for (int k = 0; k < 16; ++k) {
      const float rA = (float)Hr[k].x, rB = (float)Hr[k].y;
      const float iA = (float)Hi[k].x, iB = (float)Hi[k].y;
      v2f v; v.x = rA * rA + iA * iA; v.y = rB * rB + iB * iB;
      p2[k] = v;
    }
    finish_pair(p2, lane, bpa, out + sA * NQB, out + sB * NQB);
  }
}

extern "C" void kernel_launch(void* const* d_in, const int* in_sizes, int n_in,
                              void* d_out, int out_size, void* d_ws, size_t ws_size,
                              hipStream_t stream) {
  const float* inp = (const float*)d_in[0];
  const float* wt  = (const float*)d_in[1];
  float* out = (float*)d_out;
  const int B = in_sizes[0] / NQB;              // 32768
  const int waves = B / 4;                      // 8192 (2 pairs per wave)
  const int nblocks = (waves + 3) / 4;          // 2048
  hipLaunchKernelGGL(qlayer_kernel, dim3(nblocks), dim3(256), 0, stream,
                     inp, wt, out, B);
}

// Round 16
// 80.584 us; speedup vs baseline: 1.9985x; 1.9985x over previous
//
#include <hip/hip_runtime.h>

// 10-qubit batched statevector simulator -- packed-f16, 2 samples per wave.
// One wave (64 lanes) handles samples {gw, gw + B/2}: state = h2 Hr[16],Hi[16],
// each 32-bit VGPR holds {sampleA, sampleB} f16. Amp bits: 0..5 = lane bits,
// 6..9 = register index k. Qubit q (MSB-first) = amp bit 9-q.
//
// Round-16 = round-14 structure (straight-line, 1 pair/wave, 4096 blocks)
// + packed v2f epilogue only.
// Round-15 post-mortem: the 2-pair grid-stride loop ballooned VGPR 48->144
// (1 wave/SIMD, 11% occupancy, 181 us) -- third confirmation that ANY
// loop-over-samples structure inflates registers on this body. Straight-line
// is the stable shape. The packed epilogue (~-120 VALU instr/pair, ~30 regs
// live, below the 48-reg gate-chain peak) is kept as the single delta.

namespace {

constexpr int NQB = 10;

typedef _Float16 h2 __attribute__((ext_vector_type(2)));
typedef float v2f __attribute__((ext_vector_type(2)));

__device__ __forceinline__ float h2_as_f(h2 v) { return __builtin_bit_cast(float, v); }
__device__ __forceinline__ h2 f_as_h2(float v) { return __builtin_bit_cast(h2, v); }

__device__ __forceinline__ h2 pk2(float a, float b) {
#if __has_builtin(__builtin_amdgcn_cvt_pkrtz)
  return __builtin_bit_cast(h2, __builtin_amdgcn_cvt_pkrtz(a, b));
#else
  h2 r; r.x = (_Float16)a; r.y = (_Float16)b; return r;
#endif
}

__device__ __forceinline__ h2 hsplat(float f) {
  const _Float16 h = (_Float16)f;
  h2 r; r.x = h; r.y = h; return r;
}

__device__ __forceinline__ h2 hsel(bool c, h2 a, h2 b) {
  return f_as_h2(c ? h2_as_f(a) : h2_as_f(b));
}

template<int CTRL>
__device__ __forceinline__ float dppf(float x) {
  return __uint_as_float((unsigned)__builtin_amdgcn_update_dpp(
      0, (int)__float_as_uint(x), CTRL, 0xF, 0xF, true));
}

// Partner value x[lane ^ (1<<P)] on a 32-bit container.
// P0,P1,P3: 1 DPP (VALU). P2,P4: ds_swizzle (DS). P5: ds_bpermute (DS).
template<int P>
__device__ __forceinline__ float xorf(float x, int bpa) {
  if constexpr (P == 0) {
    return dppf<0xB1>(x);                       // quad_perm [1,0,3,2] = XOR1
  } else if constexpr (P == 1) {
    return dppf<0x4E>(x);                       // quad_perm [2,3,0,1] = XOR2
  } else if constexpr (P == 2) {
    return __uint_as_float((unsigned)__builtin_amdgcn_ds_swizzle(
        (int)__float_as_uint(x), 0x101F));      // bitmode xor=4
  } else if constexpr (P == 3) {
    return dppf<0x128>(x);                      // row_ror:8 == XOR8 within row16
  } else if constexpr (P == 4) {
    return __uint_as_float((unsigned)__builtin_amdgcn_ds_swizzle(
        (int)__float_as_uint(x), 0x401F));      // bitmode xor=16
  } else {
    return __uint_as_float((unsigned)__builtin_amdgcn_ds_bpermute(
        bpa, (int)__float_as_uint(x)));         // bpa = (lane^32)<<2
  }
}

template<int P>
__device__ __forceinline__ h2 xorh(h2 v, int bpa) {
  return f_as_h2(xorf<P>(h2_as_f(v), bpa));
}

template<int P>
__device__ __forceinline__ v2f xor2(v2f v, int bpa) {
  v2f r;
  r.x = xorf<P>(v.x, bpa);
  r.y = xorf<P>(v.y, bpa);
  return r;
}

__device__ __forceinline__ float fsin_rev(float rev) {
#if __has_builtin(__builtin_amdgcn_sinf)
  return __builtin_amdgcn_sinf(rev);
#else
  return __sinf(rev * 6.2831853071795864769f);
#endif
}
__device__ __forceinline__ float fcos_rev(float rev) {
#if __has_builtin(__builtin_amdgcn_cosf)
  return __builtin_amdgcn_cosf(rev);
#else
  return __cosf(rev * 6.2831853071795864769f);
#endif
}

__device__ __forceinline__ float clamp01(float x) {
#if __has_builtin(__builtin_amdgcn_fmed3f)
  return __builtin_amdgcn_fmed3f(x, 0.0f, 1.0f);
#else
  return fminf(fmaxf(x, 0.0f), 1.0f);
#endif
}

__device__ __forceinline__ void cmulf(float& r, float& i, float br, float bi) {
  const float tr = r * br - i * bi;
  i = r * bi + i * br;
  r = tr;
}

__device__ __forceinline__ void cmulh(h2& r, h2& i, h2 br, h2 bi) {
  const h2 tr = r*br - i*bi;
  i = r*bi + i*br;
  r = tr;
}

// u = Rot_q * (cos, sin): both rows of the per-qubit init 2-vector pair
__device__ __forceinline__ void qubit_uv(const float* m, float x,
                                         float& u0r, float& u0i,
                                         float& u1r, float& u1i) {
  const float r = 0.25f * clamp01(x);
  const float fs = fsin_rev(r), fc = fcos_rev(r);
  u0r = m[0]*fc + m[2]*fs;  u0i = m[1]*fc + m[3]*fs;
  u1r = m[4]*fc + m[6]*fs;  u1i = m[5]*fc + m[7]*fs;
}

// lane fold with layer-0 CRY chain folded: pt = 0..4, gate e = 8-pt
// (ctrl bit pt+1, tgt bit pt); w = b_ctrl ? RY(th_e)*u : u, component b_tgt.
__device__ __forceinline__ void lane_fold_cry(const float* __restrict__ xin, int lane,
                                              const float (*gm)[8], const float (*gc0)[2],
                                              float& Lr, float& Li) {
  Lr = 1.0f; Li = 0.0f;
#pragma unroll
  for (int pt = 0; pt < 5; ++pt) {
    const int q = 9 - pt, e = 8 - pt;
    float u0r, u0i, u1r, u1i;
    qubit_uv(&gm[q][0], xin[q], u0r, u0i, u1r, u1i);
    const bool bt = (lane >> pt) & 1;
    const bool bc = (lane >> (pt + 1)) & 1;
    const float c = gc0[e][0];
    const float s = bt ? gc0[e][1] : -gc0[e][1];
    const float ubr = bt ? u1r : u0r, ubi = bt ? u1i : u0i;   // u[bt]
    const float uor = bt ? u0r : u1r, uoi = bt ? u0i : u1i;   // u[1-bt]
    const float vr = c*ubr + s*uor, vi = c*ubi + s*uoi;       // (RY u)[bt]
    const float wr = bc ? vr : ubr, wi = bc ? vi : ubi;
    if (pt == 0) { Lr = wr; Li = wi; }
    else cmulf(Lr, Li, wr, wi);
  }
}

// level tables for reg bits: w[j], j = (b_ctrl<<1)|b_tgt; u rows + v = RY(th)*u
__device__ __forceinline__ void level_tab(const float* m, float c, float s,
                                          float xa, float xb,
                                          h2 (&wr)[4], h2 (&wi)[4]) {
  float a0r, a0i, a1r, a1i, b0r, b0i, b1r, b1i;
  qubit_uv(m, xa, a0r, a0i, a1r, a1i);
  qubit_uv(m, xb, b0r, b0i, b1r, b1i);
  const float va0r = c*a0r - s*a1r, va0i = c*a0i - s*a1i;
  const float va1r = s*a0r + c*a1r, va1i = s*a0i + c*a1i;
  const float vb0r = c*b0r - s*b1r, vb0i = c*b0i - s*b1i;
  const float vb1r = s*b0r + c*b1r, vb1i = s*b0i + c*b1i;
  wr[0] = pk2(a0r, b0r);  wi[0] = pk2(a0i, b0i);   // bc=0, bt=0
  wr[1] = pk2(a1r, b1r);  wi[1] = pk2(a1i, b1i);   // bc=0, bt=1
  wr[2] = pk2(va0r, vb0r); wi[2] = pk2(va0i, vb0i); // bc=1, bt=0
  wr[3] = pk2(va1r, vb1r); wi[3] = pk2(va1i, vb1i); // bc=1, bt=1
}

// ---- layer-1 gates ----

__device__ __forceinline__ void apply_diag16(h2 (&Hr)[16], h2 (&Hi)[16],
                                             h2 zr, h2 zi, const h2 (*zk)[2]) {
#pragma unroll
  for (int k = 0; k < 16; ++k) {
    const h2 kc = zk[k][0], ks = zk[k][1];
    const h2 cr = zr*kc - zi*ks;
    const h2 ci = zi*kc + zr*ks;
    const h2 tr = cr*Hr[k] - ci*Hi[k];
    const h2 ti = ci*Hr[k] + cr*Hi[k];
    Hr[k] = tr;  Hi[k] = ti;
  }
}

template<int J>
__device__ __forceinline__ void ry_reg16(h2 (&Hr)[16], h2 (&Hi)[16], h2 c, h2 s) {
#pragma unroll
  for (int k0 = 0; k0 < 16; ++k0) {
    if (k0 & J) continue;
    const int k1 = k0 | J;
    const h2 a0r = Hr[k0], a1r = Hr[k1], a0i = Hi[k0], a1i = Hi[k1];
    Hr[k0] = c*a0r - s*a1r;  Hr[k1] = s*a0r + c*a1r;
    Hi[k0] = c*a0i - s*a1i;  Hi[k1] = s*a0i + c*a1i;
  }
}

template<int P>
__device__ __forceinline__ void ry_lane16(h2 (&Hr)[16], h2 (&Hi)[16], h2 c, h2 ss,
                                          int bpa) {
#pragma unroll
  for (int k = 0; k < 16; ++k) {
    const h2 pr = xorh<P>(Hr[k], bpa);
    const h2 pi = xorh<P>(Hi[k], bpa);
    Hr[k] = c*Hr[k] + ss*pr;
    Hi[k] = c*Hi[k] + ss*pi;
  }
}

template<int CB, int J>
__device__ __forceinline__ void cry_rr(h2 (&Hr)[16], h2 (&Hi)[16], h2 c, h2 s) {
#pragma unroll
  for (int k0 = 0; k0 < 16; ++k0) {
    if ((k0 & J) || !(k0 & CB)) continue;
    const int k1 = k0 | J;
    const h2 a0r = Hr[k0], a1r = Hr[k1], a0i = Hi[k0], a1i = Hi[k1];
    Hr[k0] = c*a0r - s*a1r;  Hr[k1] = s*a0r + c*a1r;
    Hi[k0] = c*a0i - s*a1i;  Hi[k1] = s*a0i + c*a1i;
  }
}

__device__ __forceinline__ void cry_k0_l5(h2 (&Hr)[16], h2 (&Hi)[16], h2 c, h2 s,
                                          int lane, int bpa) {
  const h2 ss = hsel((lane >> 5) & 1, s, -s);
#pragma unroll
  for (int k = 1; k < 16; k += 2) {
    const h2 pr = xorh<5>(Hr[k], bpa);
    const h2 pi = xorh<5>(Hi[k], bpa);
    Hr[k] = c*Hr[k] + ss*pr;
    Hi[k] = c*Hi[k] + ss*pi;
  }
}

template<int PC, int PT>
__device__ __forceinline__ void cry_ll(h2 (&Hr)[16], h2 (&Hi)[16], h2 c, h2 s,
                                       h2 HONE, h2 HZERO, int lane, int bpa) {
  const bool ctrl = (lane >> PC) & 1;
  const h2 ce = hsel(ctrl, c, HONE);
  const h2 se = hsel(ctrl, s, HZERO);
  const h2 ss = hsel((lane >> PT) & 1, se, -se);
#pragma unroll
  for (int k = 0; k < 16; ++k) {
    const h2 pr = xorh<PT>(Hr[k], bpa);
    const h2 pi = xorh<PT>(Hi[k], bpa);
    Hr[k] = ce*Hr[k] + ss*pr;
    Hi[k] = ce*Hi[k] + ss*pi;
  }
}

__device__ __forceinline__ void cry_l0_r8(h2 (&Hr)[16], h2 (&Hi)[16], h2 c, h2 s,
                                          h2 HONE, h2 HZERO, int lane) {
  const bool ctrl = lane & 1;
  const h2 ce = hsel(ctrl, c, HONE);
  const h2 se = hsel(ctrl, s, HZERO);
#pragma unroll
  for (int k0 = 0; k0 < 8; ++k0) {
    const int k1 = k0 + 8;
    const h2 a0r = Hr[k0], a1r = Hr[k1], a0i = Hi[k0], a1i = Hi[k1];
    Hr[k0] = ce*a0r - se*a1r;  Hr[k1] = se*a0r + ce*a1r;
    Hi[k0] = ce*a0i - se*a1i;  Hi[k1] = se*a0i + ce*a1i;
  }
}

// ---- epilogue per PAIR: packed v2f {A,B} probs -> 10 expvals each, write ----
__device__ __forceinline__ void finish_pair(const v2f (&p)[16], int lane, int bpa,
                                            float* __restrict__ outA,
                                            float* __restrict__ outB) {
  v2f t[8], T[4];
  v2f e6 = {0.0f, 0.0f};
#pragma unroll
  for (int j = 0; j < 8; ++j) { t[j] = p[2*j] + p[2*j+1]; e6 += p[2*j] - p[2*j+1]; }
  v2f e7 = {0.0f, 0.0f};
#pragma unroll
  for (int j = 0; j < 4; ++j) { T[j] = t[2*j] + t[2*j+1]; e7 += t[2*j] - t[2*j+1]; }
  const v2f U0 = T[0] + T[1], U1 = T[2] + T[3];
  const v2f e8 = (T[0] - T[1]) + (T[2] - T[3]);
  const v2f tot = U0 + U1;
  const v2f e9 = U0 - U1;

  float sgn[6];
#pragma unroll
  for (int q = 0; q < 6; ++q) sgn[q] = ((lane >> q) & 1) ? -1.0f : 1.0f;

  v2f E[6];
  v2f tt = tot;
#define QSTEP(P)                                                   \
  {                                                                \
    const v2f pt = xor2<P>(tt, bpa);                               \
    E[P] = (tt - pt) * sgn[P];                                     \
    tt += pt;                                                      \
    _Pragma("unroll")                                              \
    for (int jj = 0; jj < P; ++jj) E[jj] += xor2<P>(E[jj], bpa);   \
  }
  QSTEP(0) QSTEP(1) QSTEP(2) QSTEP(3) QSTEP(4) QSTEP(5)
#undef QSTEP

  v2f a6 = e6, a7 = e7, a8 = e8, a9 = e9;
#define RSTEP(P)                 \
  a6 += xor2<P>(a6, bpa);        \
  a7 += xor2<P>(a7, bpa);        \
  a8 += xor2<P>(a8, bpa);        \
  a9 += xor2<P>(a9, bpa);
  RSTEP(0) RSTEP(1) RSTEP(2) RSTEP(3) RSTEP(4) RSTEP(5)
#undef RSTEP

  // out[q], q = 9 - p: q=0..3 <- bits 9,8,7,6 ; q=4..9 <- E[5..0]
  if (lane < 10) {
    v2f v = a9;
    v = (lane == 1) ? a8 : v;
    v = (lane == 2) ? a7 : v;
    v = (lane == 3) ? a6 : v;
    v = (lane == 4) ? E[5] : v;
    v = (lane == 5) ? E[4] : v;
    v = (lane == 6) ? E[3] : v;
    v = (lane == 7) ? E[2] : v;
    v = (lane == 8) ? E[1] : v;
    v = (lane == 9) ? E[0] : v;
    outA[lane] = v.x;
    outB[lane] = v.y;
  }
}

} // namespace

__global__ __launch_bounds__(256)
void qlayer_kernel(const float* __restrict__ inp,   // (B, 10)
                   const float* __restrict__ wt,    // (80,)
                   float* __restrict__ out,         // (B, 10)
                   int B)
{
  __shared__ float gm[10][8];        // layer-0 Rot matrices (f32)
  __shared__ float gc0[10][2];       // layer-0 CRY {c,s} f32 (used in init fold)
  __shared__ h2 gch1[10][2];         // layer-1 CRY {c,s} splats
  __shared__ h2 grot1h[10][2];       // layer-1 RY {c,s} splats
  __shared__ h2 gdk[2][16][2];       // layer-1 diag reg phases {c,s} splats
  __shared__ float gzlane[2][64][2]; // per-lane diag phase (c,s): [0]=phi,[1]=omega

  const int tid = threadIdx.x;

  // ---- setup (disjoint thread ranges) ----
  if (tid < 10) {
    // layer-0 Rot(phi, theta, omega) = RZ(omega) RY(theta) RZ(phi)
    const int w = 3 * tid;
    const float phi = wt[w], th = wt[w + 1], om = wt[w + 2];
    float s, c, sa, ca, sb, cb;
    __sincosf(0.5f * th, &s, &c);
    __sincosf(0.5f * (phi + om), &sa, &ca);
    __sincosf(0.5f * (phi - om), &sb, &cb);
    gm[tid][0] =  c * ca;  gm[tid][1] = -c * sa;   // u00
    gm[tid][2] = -s * cb;  gm[tid][3] = -s * sb;   // u01
    gm[tid][4] =  s * cb;  gm[tid][5] = -s * sb;   // u10
    gm[tid][6] =  c * ca;  gm[tid][7] =  c * sa;   // u11
  } else if (tid >= 16 && tid < 26) {
    const int e = tid - 16;                        // layer-0 CRY
    float s, c;
    __sincosf(0.5f * wt[30 + e], &s, &c);
    gc0[e][0] = c;
    gc0[e][1] = s;
  } else if (tid >= 32 && tid < 42) {
    const int e = tid - 32;                        // layer-1 CRY
    float s, c;
    __sincosf(0.5f * wt[70 + e], &s, &c);
    gch1[e][0] = hsplat(c);
    gch1[e][1] = hsplat(s);
  } else if (tid >= 48 && tid < 58) {
    const int q = tid - 48;
    float s, c;
    __sincosf(0.5f * wt[41 + 3 * q], &s, &c);      // layer-1 theta_q
    grot1h[q][0] = hsplat(c);
    grot1h[q][1] = hsplat(s);
  } else if (tid >= 64 && tid < 96) {
    // layer-1 diag reg tables: k bit0<->q3(+9), bit1<->q2(+6), bit2<->q1(+3), bit3<->q0(+0)
    const int t = tid - 64;
    const int d = t >> 4, k = t & 15;
    const int wb = d ? 42 : 40;
    float ang = 0.0f;
    if (k & 1) ang += wt[wb + 9];
    if (k & 2) ang += wt[wb + 6];
    if (k & 4) ang += wt[wb + 3];
    if (k & 8) ang += wt[wb + 0];
    float s, c;
    __sincosf(ang, &s, &c);
    gdk[d][k][0] = hsplat(c);
    gdk[d][k][1] = hsplat(s);
  } else if (tid >= 128) {
    // per-lane diag phase (lane bit p <-> qubit 9-p)
    const int d = (tid - 128) >> 6, ln = tid & 63;
    const int wb = d ? 42 : 40;
    float ang = 0.0f;
    if (ln & 1)  ang += wt[wb + 27];
    if (ln & 2)  ang += wt[wb + 24];
    if (ln & 4)  ang += wt[wb + 21];
    if (ln & 8)  ang += wt[wb + 18];
    if (ln & 16) ang += wt[wb + 15];
    if (ln & 32) ang += wt[wb + 12];
    float s, c;
    __sincosf(ang, &s, &c);
    gzlane[d][ln][0] = c;
    gzlane[d][ln][1] = s;
  }
  __syncthreads();

  const int lane = tid & 63;
  const int bpa = (lane ^ 32) << 2;
  const int half = B >> 1;
  const int gw = blockIdx.x * 4 + (tid >> 6);
  if (gw >= half) return;
  const int sA = gw, sB = gw + half;
  const float* xA = inp + sA * NQB;
  const float* xB = inp + sB * NQB;

  const h2 HONE  = hsplat(1.0f);
  const h2 HZERO = hsplat(0.0f);

  // ---- init: product state through (embedding RY + layer-0 Rot + layer-0
  // CRY gates (0,1)..(8,9)), built as pair-factor product. ----

  // lane part (bits 0..4, gates e=8..4)
  float LrA, LiA, LrB, LiB;
  lane_fold_cry(xA, lane, gm, gc0, LrA, LiA);
  lane_fold_cry(xB, lane, gm, gc0, LrB, LiB);

  // W5: bit 5 factor w_5(b6, b5) -- gate e=3 (ctrl bit6=reg k0), qubit 4
  h2 W5ur, W5ui, W5vr, W5vi;
  {
    float a0r,a0i,a1r,a1i, b0r,b0i,b1r,b1i;
    qubit_uv(&gm[4][0], xA[4], a0r,a0i,a1r,a1i);
    qubit_uv(&gm[4][0], xB[4], b0r,b0i,b1r,b1i);
    const bool bt = (lane >> 5) & 1;
    const float c = gc0[3][0];
    const float s = bt ? gc0[3][1] : -gc0[3][1];
    const float uArr = bt ? a1r : a0r, uAri = bt ? a1i : a0i;
    const float uAor = bt ? a0r : a1r, uAoi = bt ? a0i : a1i;
    const float uBrr = bt ? b1r : b0r, uBri = bt ? b1i : b0i;
    const float uBor = bt ? b0r : b1r, uBoi = bt ? b0i : b1i;
    W5ur = pk2(uArr, uBrr);  W5ui = pk2(uAri, uBri);
    W5vr = pk2(c*uArr + s*uAor, c*uBrr + s*uBor);
    W5vi = pk2(c*uAri + s*uAoi, c*uBri + s*uBoi);
  }

  // seed: bit 9 (qubit 0): H[k=8*b9] = L * u9[b9]
  h2 Hr[16], Hi[16];
  {
    float a0r,a0i,a1r,a1i, b0r,b0i,b1r,b1i;
    qubit_uv(&gm[0][0], xA[0], a0r,a0i,a1r,a1i);
    qubit_uv(&gm[0][0], xB[0], b0r,b0i,b1r,b1i);
    float t0rA = LrA, t0iA = LiA;  cmulf(t0rA, t0iA, a0r, a0i);
    float t1rA = LrA, t1iA = LiA;  cmulf(t1rA, t1iA, a1r, a1i);
    float t0rB = LrB, t0iB = LiB;  cmulf(t0rB, t0iB, b0r, b0i);
    float t1rB = LrB, t1iB = LiB;  cmulf(t1rB, t1iB, b1r, b1i);
    Hr[0] = pk2(t0rA, t0rB);  Hi[0] = pk2(t0iA, t0iB);
    Hr[8] = pk2(t1rA, t1rB);  Hi[8] = pk2(t1iA, t1iB);
  }

  // level bit 8 (qubit 1, gate e=0, ctrl = bit 9): parents {0,8}
  {
    h2 wr[4], wi[4];
    level_tab(&gm[1][0], gc0[0][0], gc0[0][1], xA[1], xB[1], wr, wi);
    Hr[4]  = Hr[0]; Hi[4]  = Hi[0]; cmulh(Hr[4],  Hi[4],  wr[1], wi[1]);  // b9=0,b8=1
    cmulh(Hr[0],  Hi[0],  wr[0], wi[0]);                                  // b9=0,b8=0
    Hr[12] = Hr[8]; Hi[12] = Hi[8]; cmulh(Hr[12], Hi[12], wr[3], wi[3]);  // b9=1,b8=1
    cmulh(Hr[8],  Hi[8],  wr[2], wi[2]);                                  // b9=1,b8=0
  }

  // level bit 7 (qubit 2, gate e=1, ctrl = bit 8): parents {0,4,8,12}
  {
    h2 wr[4], wi[4];
    level_tab(&gm[2][0], gc0[1][0], gc0[1][1], xA[2], xB[2], wr, wi);
#pragma unroll
    for (int k = 0; k < 16; k += 4) {
      const int j = ((k >> 2) & 1) << 1;           // b8
      Hr[k+2] = Hr[k]; Hi[k+2] = Hi[k]; cmulh(Hr[k+2], Hi[k+2], wr[j|1], wi[j|1]);
      cmulh(Hr[k], Hi[k], wr[j], wi[j]);
    }
  }

  // level bit 6 (qubit 3, gate e=2, ctrl = bit 7) x W5(b6): parents {0,2,..,14}
  {
    h2 wr[4], wi[4];
    level_tab(&gm[3][0], gc0[2][0], gc0[2][1], xA[3], xB[3], wr, wi);
    cmulh(wr[0], wi[0], W5ur, W5ui);
    cmulh(wr[1], wi[1], W5vr, W5vi);
    cmulh(wr[2], wi[2], W5ur, W5ui);
    cmulh(wr[3], wi[3], W5vr, W5vi);
#pragma unroll
    for (int k = 0; k < 16; k += 2) {
      const int j = ((k >> 1) & 1) << 1;           // b7
      Hr[k+1] = Hr[k]; Hi[k+1] = Hi[k]; cmulh(Hr[k+1], Hi[k+1], wr[j|1], wi[j|1]);
      cmulh(Hr[k], Hi[k], wr[j], wi[j]);
    }
  }

  // ---- layer 0: final ring gate (9,0): ctrl lane bit 0, tgt reg bit 3 ----
  cry_l0_r8(Hr, Hi, hsplat(gc0[9][0]), hsplat(gc0[9][1]), HONE, HZERO, lane);

  // ---- layer 1: D_phi -> real RY layer -> D_omega -> CRY ring ----
  {
    const float2 zp = *(const float2*)&gzlane[0][lane][0];
    apply_diag16(Hr, Hi, hsplat(zp.x), hsplat(zp.y), &gdk[0][0]);
    ry_reg16<8>(Hr, Hi, grot1h[0][0], grot1h[0][1]);          // q=0, k3
    ry_reg16<4>(Hr, Hi, grot1h[1][0], grot1h[1][1]);          // q=1, k2
    ry_reg16<2>(Hr, Hi, grot1h[2][0], grot1h[2][1]);          // q=2, k1
    ry_reg16<1>(Hr, Hi, grot1h[3][0], grot1h[3][1]);          // q=3, k0
    {
      const h2 s5 = grot1h[4][1];
      ry_lane16<5>(Hr, Hi, grot1h[4][0], hsel((lane >> 5) & 1, s5, -s5), bpa);
      const h2 s4 = grot1h[5][1];
      ry_lane16<4>(Hr, Hi, grot1h[5][0], hsel((lane >> 4) & 1, s4, -s4), bpa);
      const h2 s3 = grot1h[6][1];
      ry_lane16<3>(Hr, Hi, grot1h[6][0], hsel((lane >> 3) & 1, s3, -s3), bpa);
      const h2 s2 = grot1h[7][1];
      ry_lane16<2>(Hr, Hi, grot1h[7][0], hsel((lane >> 2) & 1, s2, -s2), bpa);
      const h2 s1 = grot1h[8][1];
      ry_lane16<1>(Hr, Hi, grot1h[8][0], hsel((lane >> 1) & 1, s1, -s1), bpa);
      const h2 s0 = grot1h[9][1];
      ry_lane16<0>(Hr, Hi, grot1h[9][0], hsel(lane & 1, s0, -s0), bpa);
    }
    const float2 zo = *(const float2*)&gzlane[1][lane][0];
    apply_diag16(Hr, Hi, hsplat(zo.x), hsplat(zo.y), &gdk[1][0]);

    const h2 (*cc)[2] = &gch1[0];
    cry_rr<8, 4>(Hr, Hi, cc[0][0], cc[0][1]);                 // (q0,q1)
    cry_rr<4, 2>(Hr, Hi, cc[1][0], cc[1][1]);                 // (q1,q2)
    cry_rr<2, 1>(Hr, Hi, cc[2][0], cc[2][1]);                 // (q2,q3)
    cry_k0_l5   (Hr, Hi, cc[3][0], cc[3][1], lane, bpa);      // (q3,q4)
    cry_ll<5, 4>(Hr, Hi, cc[4][0], cc[4][1], HONE, HZERO, lane, bpa);
    cry_ll<4, 3>(Hr, Hi, cc[5][0], cc[5][1], HONE, HZERO, lane, bpa);
    cry_ll<3, 2>(Hr, Hi, cc[6][0], cc[6][1], HONE, HZERO, lane, bpa);
    cry_ll<2, 1>(Hr, Hi, cc[7][0], cc[7][1], HONE, HZERO, lane, bpa);
    cry_ll<1, 0>(Hr, Hi, cc[8][0], cc[8][1], HONE, HZERO, lane, bpa);
    cry_l0_r8   (Hr, Hi, cc[9][0], cc[9][1], HONE, HZERO, lane);  // (q9,q0)
  }

  // ---- probabilities (packed f32 {A,B}) and epilogue ----
  v2f p2[16];
#pragma unroll
  for (int k = 0; k < 16; ++k) {
    const float rA = (float)Hr[k].x, rB = (float)Hr[k].y;
    const float iA = (float)Hi[k].x, iB = (float)Hi[k].y;
    v2f v; v.x = rA * rA + iA * iA; v.y = rB * rB + iB * iB;
    p2[k] = v;
  }
  finish_pair(p2, lane, bpa, out + sA * NQB, out + sB * NQB);
}

extern "C" void kernel_launch(void* const* d_in, const int* in_sizes, int n_in,
                              void* d_out, int out_size, void* d_ws, size_t ws_size,
                              hipStream_t stream) {
  const float* inp = (const float*)d_in[0];
  const float* wt  = (const float*)d_in[1];
  float* out = (float*)d_out;
  const int B = in_sizes[0] / NQB;              // 32768
  const int pairs = B / 2;                      // 16384 waves
  const int nblocks = (pairs + 3) / 4;          // 4096
  hipLaunchKernelGGL(qlayer_kernel, dim3(nblocks), dim3(256), 0, stream,
                     inp, wt, out, B);
}